// Round 1
// baseline (2601.065 us; speedup 1.0000x reference)
//
#include <hip/hip_runtime.h>
#include <math.h>

// Problem constants
#define DD 512
#define NN 128
#define XBASE 385   // D - N + 1 ; xmax_k = XBASE + k

// Workspace layout (in 4-byte elements)
#define OFF_M      0            // 512*512 chain matrix (G, eliminated in place on trailing part)
#define OFF_LP     262144       // 512*32  scaled L panel (current stage)
#define OFF_UP     278528       // 32*512  U12 row block (current stage)
#define OFF_CPIV   294912       // 512     chain pivots (unshadowed diag at elimination time)
#define OFF_SHAD   295424       // 128     running shadow diagonals (value with -1 applied at start)
#define OFF_SSNAP  295552       // 16*128  shadow snapshot at start of each stage
#define OFF_FPIV   297600       // 128*512 fork pivots
#define OFF_LOG    363136       // 128     per-row log(picked)
#define OFF_MI     363264       // 768 ints: [0..127]=p, [+128]=c, [+256]=x, [+384]=j0, [+512]=s, [+640]=pool off
#define OFF_POSMAP 364032       // 512 ints: site -> k or -1
#define OFF_MISC   364544       // ints: [0]=p127
#define OFF_FORK   364608       // fork snapshot pool (sum of s_k^2 floats, ~30 MB typical)

// ---------------------------------------------------------------- G = I - P P^T
__global__ void k_build(const float* __restrict__ P, float* __restrict__ ws) {
    __shared__ float Pr[32][129];
    __shared__ float Pc[32][129];
    int r0 = blockIdx.x * 32, c0 = blockIdx.y * 32, tid = threadIdx.x;
    for (int idx = tid; idx < 32 * 128; idx += 256) {
        int r = idx >> 7, t = idx & 127;
        Pr[r][t] = P[(r0 + r) * NN + t];
        Pc[r][t] = P[(c0 + r) * NN + t];
    }
    __syncthreads();
    int cl = tid & 31, rl0 = tid >> 5;
    for (int e = 0; e < 4; ++e) {
        int rl = rl0 + e * 8;
        float acc = 0.0f;
#pragma unroll 8
        for (int t = 0; t < 128; ++t) acc = fmaf(Pr[rl][t], Pc[cl][t], acc);
        int gr = r0 + rl, gc = c0 + cl;
        ws[OFF_M + gr * DD + gc] = ((gr == gc) ? 1.0f : 0.0f) - acc;
    }
}

// ---------------------------------------------------------------- per-k metadata + shadow init
__global__ void k_meta(const int* __restrict__ pos, float* __restrict__ ws) {
    int* mi   = (int*)ws + OFF_MI;
    int* pm   = (int*)ws + OFF_POSMAP;
    int* misc = (int*)ws + OFF_MISC;
    __shared__ int sS[128];
    int k = threadIdx.x;           // blockDim.x == 128
    int p = pos[k];
    mi[k] = p;
    mi[128 + k] = (k == 0) ? 0 : (pos[k - 1] + 1);   // c_k = xmin_k
    int x = XBASE + k;                                // xmax_k
    mi[256 + k] = x;
    int j0 = (p >> 5) << 5;                           // fork start column (stage boundary)
    mi[384 + k] = j0;
    int s = x - j0;                                   // fork submatrix side, 1..416
    mi[512 + k] = s;
    sS[k] = s * s;
    float g = ws[OFF_M + p * DD + p];
    ws[OFF_SHAD + k]  = g - 1.0f;                     // fl((G_pp) - 1): matches reference init order
    ws[OFF_SSNAP + k] = g - 1.0f;                     // stage-0 snapshot
    for (int i = k; i < 512; i += 128) pm[i] = -1;
    __syncthreads();
    pm[p] = k;
    if (k == 0) {
        int acc = 0;
        for (int i = 0; i < 128; ++i) { mi[640 + i] = acc; acc += sS[i]; }
        misc[0] = pos[127];
    }
}

// ---------------------------------------------------------------- stage-0 fork snapshots (raw G regions)
__global__ void k_snap0(float* __restrict__ ws) {
    const int* mi = (const int*)ws + OFF_MI;
    int r0 = blockIdx.x * 32, c0 = blockIdx.y * 32, tid = threadIdx.x;
    int cl = tid & 31, rl0 = tid >> 5;
    for (int k = 0; k < 128; ++k) {
        if (mi[384 + k] != 0) continue;
        int x = mi[256 + k];
        if (r0 >= x || c0 >= x) continue;
        int s = mi[512 + k];
        float* buf = ws + OFF_FORK + mi[640 + k];
        for (int e = 0; e < 4; ++e) {
            int gr = r0 + rl0 + e * 8, gc = c0 + cl;
            if (gr < x && gc < x) buf[gr * s + gc] = ws[OFF_M + gr * DD + gc];
        }
    }
}

// ---------------------------------------------------------------- chain panel factorization (1 WG)
__global__ void __launch_bounds__(1024) k_panel(float* __restrict__ ws, int t) {
    const int* misc = (const int*)ws + OFF_MISC;
    int j0 = t * 32;
    if (j0 > misc[0]) return;                         // chain only needed through p127
    const int* pm = (const int*)ws + OFF_POSMAP;
    __shared__ float pan[512][33];                    // panel columns, padded (column access)
    __shared__ float ustrip[32][480];                 // U12 rows (row-wise access only)
    __shared__ float shad[128];
    __shared__ int   chf[32];
    __shared__ float pivsh;
    int tid = threadIdx.x;
    int h = DD - j0, jn = j0 + 32, w = DD - jn;
    for (int idx = tid; idx < h * 32; idx += 1024) {
        int r = idx >> 5, jj = idx & 31;
        pan[r][jj] = ws[OFF_M + (j0 + r) * DD + j0 + jj];
    }
    for (int idx = tid; idx < 32 * w; idx += 1024) {
        int jj = idx / w, cc = idx % w;
        ustrip[jj][cc] = ws[OFF_M + (j0 + jj) * DD + jn + cc];
    }
    if (tid < 128) { float sv = ws[OFF_SHAD + tid]; shad[tid] = sv; ws[OFF_SSNAP + t * 128 + tid] = sv; }
    if (tid < 32) chf[tid] = pm[j0 + tid];
    __syncthreads();
    for (int jj = 0; jj < 32; ++jj) {
        if (tid == 0) {
            float d = pan[jj][jj];
            ws[OFF_CPIV + j0 + jj] = d;               // unshadowed pivot: A_{k(j)}'s pivot, used by row k(j)
            pivsh = (chf[jj] >= 0) ? shad[chf[jj]] : d;  // chain eliminates chosen cols with shadowed pivot
        }
        __syncthreads();
        float pv = pivsh;
        for (int r = jj + 1 + tid; r < h; r += 1024) pan[r][jj] = pan[r][jj] / pv;
        __syncthreads();
        int nc = 31 - jj, nr = h - jj - 1;
        for (int idx = tid; idx < nr * nc; idx += 1024) {
            int r = jj + 1 + idx / nc, cc = jj + 1 + idx % nc;
            pan[r][cc] = fmaf(-pan[r][jj], pan[jj][cc], pan[r][cc]);
        }
        for (int idx = tid; idx < nc * w; idx += 1024) {
            int rr = jj + 1 + idx / w, cc = idx % w;
            ustrip[rr][cc] = fmaf(-pan[rr][jj], ustrip[jj][cc], ustrip[rr][cc]);
        }
        if (tid < 32 && tid > jj && chf[tid] >= 0)    // shadows of chosen diag entries inside panel
            shad[chf[tid]] = fmaf(-pan[tid][jj], pan[jj][tid], shad[chf[tid]]);
        __syncthreads();
    }
    for (int idx = tid; idx < (h - 32) * 32; idx += 1024) {
        int r = 32 + (idx >> 5), jj = idx & 31;
        ws[OFF_LP + (j0 + r) * 32 + jj] = pan[r][jj];
    }
    for (int idx = tid; idx < 32 * w; idx += 1024) {
        int jj = idx / w, cc = idx % w;
        ws[OFF_UP + jj * DD + jn + cc] = ustrip[jj][cc];
    }
    if (tid < 128) ws[OFF_SHAD + tid] = shad[tid];
}

// ---------------------------------------------------------------- chain trailing update + next-stage snapshots
__global__ void k_trail(float* __restrict__ ws, int t) {
    const int* misc = (const int*)ws + OFF_MISC;
    int j0 = t * 32, jn = j0 + 32;
    if (jn > misc[0]) return;                         // no later chain stages / forks needed
    const int* mi = (const int*)ws + OFF_MI;
    const int* pm = (const int*)ws + OFF_POSMAP;
    int r0 = blockIdx.x * 32, c0 = blockIdx.y * 32, tid = threadIdx.x;
    if (r0 < jn || c0 < jn) return;
    __shared__ float Mt[32][33], Lt[32][33], Ut[32][33];
    int cl = tid & 31, rl0 = tid >> 5;
    for (int e = 0; e < 4; ++e) {
        int rl = rl0 + e * 8;
        Mt[rl][cl] = ws[OFF_M + (r0 + rl) * DD + c0 + cl];
        Lt[rl][cl] = ws[OFF_LP + (r0 + rl) * 32 + cl];
        Ut[rl][cl] = ws[OFF_UP + rl * DD + c0 + cl];
    }
    __syncthreads();
    for (int e = 0; e < 4; ++e) {
        int rl = rl0 + e * 8;
        float acc = Mt[rl][cl];
#pragma unroll
        for (int jj = 0; jj < 32; ++jj) acc = fmaf(-Lt[rl][jj], Ut[jj][cl], acc);
        Mt[rl][cl] = acc;
        int gr = r0 + rl, gc = c0 + cl;
        if (gr == gc) {                               // shadow gets identical ordered update chain
            int kk = pm[gr];
            if (kk >= 0) {
                float sv = ws[OFF_SHAD + kk];
#pragma unroll
                for (int jj = 0; jj < 32; ++jj) sv = fmaf(-Lt[rl][jj], Ut[jj][cl], sv);
                ws[OFF_SHAD + kk] = sv;
            }
        }
        ws[OFF_M + gr * DD + gc] = acc;
    }
    __syncthreads();
    // snapshot regions for forks starting at stage t+1 (state: columns 0..jn-1 eliminated)
    for (int k = 0; k < 128; ++k) {
        if (mi[384 + k] != jn) continue;
        int x = mi[256 + k];
        if (r0 >= x || c0 >= x) continue;
        int s = mi[512 + k];
        float* buf = ws + OFF_FORK + mi[640 + k];
        for (int e = 0; e < 4; ++e) {
            int gr = r0 + rl0 + e * 8, gc = c0 + cl;
            if (gr < x && gc < x) buf[(gr - jn) * s + (gc - jn)] = Mt[rl0 + e * 8][cl];
        }
    }
}

// ---------------------------------------------------------------- per-row fork: blocked LU of snapshot
__global__ void __launch_bounds__(1024) k_fork(float* __restrict__ ws) {
    const int* mi = (const int*)ws + OFF_MI;
    const int* pm = (const int*)ws + OFF_POSMAP;
    int k = blockIdx.x;
    int p = mi[k], x = mi[256 + k], j0 = mi[384 + k], s = mi[512 + k];
    if (p >= x - 1) return;                           // no pivots beyond p_k needed
    float* buf = ws + OFF_FORK + mi[640 + k];
    float* fpv = ws + OFF_FPIV + k * DD;
    int tstage = j0 >> 5;
    __shared__ float fpan[416][33];
    __shared__ float fstrip[32][385];
    __shared__ float lsh[32];
    __shared__ int   chflag[32];
    __shared__ float pivsh;
    int tid = threadIdx.x;
    if (tid < 32) {
        int g = j0 + tid;
        int kk = (g < DD) ? pm[g] : -1;
        chflag[tid] = (kk >= 0 && g < p) ? kk : -1;   // chosen columns BEFORE p_k use shadow pivots
        lsh[tid] = (kk >= 0 && g < p) ? ws[OFF_SSNAP + tstage * 128 + kk] : 0.0f;
    }
    __syncthreads();
    int xl = s - 1;                                   // local index of column x-1 (record-only)
    bool done = false;
    for (int pf0 = 0; pf0 < s && !done; pf0 += 32) {
        int pw = (s - pf0 < 32) ? (s - pf0) : 32;
        int hl = s - pf0;
        int wl = s - pf0 - pw;
        for (int idx = tid; idx < hl * pw; idx += 1024) {
            int r = idx / pw, jj = idx % pw;
            fpan[r][jj] = buf[(pf0 + r) * s + pf0 + jj];
        }
        for (int idx = tid; idx < pw * wl; idx += 1024) {
            int jj = idx / wl, cc = idx % wl;
            fstrip[jj][cc] = buf[(pf0 + jj) * s + pf0 + pw + cc];
        }
        __syncthreads();
        for (int jj = 0; jj < pw; ++jj) {
            int lc = pf0 + jj;
            int g = j0 + lc;
            if (tid == 0) {
                float d = fpan[jj][jj];
                if (g > p) fpv[g] = d;                // A_k pivot at column g (pre-elimination diag)
                float pv = d;
                if (pf0 == 0 && chflag[jj] >= 0) pv = lsh[jj];
                pivsh = pv;
            }
            __syncthreads();
            if (lc >= xl) { done = true; break; }     // last pivot recorded; nothing more to eliminate
            float pv = pivsh;
            for (int r = jj + 1 + tid; r < hl; r += 1024) fpan[r][jj] = fpan[r][jj] / pv;
            __syncthreads();
            int nc = pw - jj - 1, nr = hl - jj - 1;
            for (int idx = tid; idx < nr * nc; idx += 1024) {
                int r = jj + 1 + idx / nc, cc = jj + 1 + idx % nc;
                fpan[r][cc] = fmaf(-fpan[r][jj], fpan[jj][cc], fpan[r][cc]);
            }
            for (int idx = tid; idx < nc * wl; idx += 1024) {
                int rr = jj + 1 + idx / wl, cc = idx % wl;
                fstrip[rr][cc] = fmaf(-fpan[rr][jj], fstrip[jj][cc], fstrip[rr][cc]);
            }
            if (pf0 == 0 && tid < 32 && tid > jj && chflag[tid] >= 0)
                lsh[tid] = fmaf(-fpan[tid][jj], fpan[jj][tid], lsh[tid]);
            __syncthreads();
        }
        if (done) break;
        int tw = wl;                                  // trailing update in global snapshot buffer
        for (int idx = tid; idx < tw * tw; idx += 1024) {
            int r = pf0 + pw + idx / tw, c = pf0 + pw + idx % tw;
            float acc = buf[r * s + c];
            if (pw == 32) {
#pragma unroll
                for (int jj = 0; jj < 32; ++jj)
                    acc = fmaf(-fpan[r - pf0][jj], fstrip[jj][c - pf0 - pw], acc);
            } else {
                for (int jj = 0; jj < pw; ++jj)
                    acc = fmaf(-fpan[r - pf0][jj], fstrip[jj][c - pf0 - pw], acc);
            }
            buf[r * s + c] = acc;
        }
        __syncthreads();
    }
}

// ---------------------------------------------------------------- probs rows: cumprod + threshold + log term
__global__ void k_epilogue(float* __restrict__ ws, float* __restrict__ out) {
    const int* mi = (const int*)ws + OFF_MI;
    int k = blockIdx.x, tid = threadIdx.x;
    __shared__ float row[512];
    for (int i = tid; i < 512; i += 256) row[i] = 0.0f;
    __syncthreads();
    if (tid == 0) {
        int c = mi[128 + k], p = mi[k], x = mi[256 + k];
        float cp = 1.0f;                              // exclusive prefix product of pivots (jnp.cumprod order)
        for (int i = c; i < x; ++i) {
            float pv = (i <= p) ? ws[OFF_CPIV + i] : ws[OFF_FPIV + k * DD + i];
            float pr = cp * (1.0f - pv);
            row[i] = (fabsf(pr) > 1e-15f) ? pr : 0.0f;
            cp = cp * pv;
        }
        ws[OFF_LOG + k] = logf(row[p]);
    }
    __syncthreads();
    for (int i = tid; i < 512; i += 256) out[k * DD + i] = row[i];
}

__global__ void k_logsum(float* __restrict__ ws, float* __restrict__ out) {
    if (threadIdx.x == 0) {
        double sacc = 0.0;
        for (int i = 0; i < 128; ++i) sacc += (double)ws[OFF_LOG + i];
        out[65536] = (float)sacc;
    }
}

// ----------------------------------------------------------------
extern "C" void kernel_launch(void* const* d_in, const int* in_sizes, int n_in,
                              void* d_out, int out_size, void* d_ws, size_t ws_size,
                              hipStream_t stream) {
    const float* P   = (const float*)d_in[0];
    const int*   pos = (const int*)d_in[1];
    float* ws  = (float*)d_ws;
    float* out = (float*)d_out;

    k_build<<<dim3(16, 16), 256, 0, stream>>>(P, ws);
    k_meta<<<1, 128, 0, stream>>>(pos, ws);
    k_snap0<<<dim3(16, 16), 256, 0, stream>>>(ws);
    for (int t = 0; t < 16; ++t) {
        k_panel<<<1, 1024, 0, stream>>>(ws, t);
        if (t < 15) k_trail<<<dim3(16, 16), 256, 0, stream>>>(ws, t);
    }
    k_fork<<<128, 1024, 0, stream>>>(ws);
    k_epilogue<<<128, 256, 0, stream>>>(ws, out);
    k_logsum<<<1, 64, 0, stream>>>(ws, out);
}